// Round 7
// baseline (817.973 us; speedup 1.0000x reference)
//
#include <hip/hip_runtime.h>
#include <hip/hip_fp16.h>

#define TPB 256
constexpr float PI_F = 3.14159265358979323846f;

constexpr int NF = 4096;           // complex FFT length (real n = 8192)
constexpr int KSTR = 4104;         // __half2 stride per spectral row (4097 used)

// workspace layout (bytes) — ws_size is 256 MiB; total here ≈ 212.8 MiB
constexpr size_t XT_OFF  = 0;                                     // xT [2][1024][4096] f32 = 32 MiB
constexpr size_t XF_OFF  = 33554432ull;                           // Xf fp16 [2048][KSTR] = 33.6 MiB
constexpr size_t Y_OFF   = XF_OFF + 2048ull * KSTR * 4;           // y bf16 [2][4][1024][4096] = 64 MiB
constexpr size_t KF_OFF  = Y_OFF + 2ull * 4 * 1024 * 4096 * 2;    // Kf fp16 [4096][KSTR] = 67.2 MiB
constexpr size_t WOH_OFF = KF_OFF + 4096ull * KSTR * 4;           // out_w hi/lo (8+8 MiB)
constexpr size_t WOL_OFF = WOH_OFF + 4096ull * 1024 * 2;
constexpr size_t WS_NEED = WOL_OFF + 4096ull * 1024 * 2;
// aliased into KF region (dead after gemm_in): Uh 16M | Ul 16M | Wih 2M | Wil 2M
constexpr size_t UH_OFF  = KF_OFF;
constexpr size_t UL_OFF  = UH_OFF + 8192ull * 1024 * 2;
constexpr size_t WIH_OFF = UL_OFF + 8192ull * 1024 * 2;
constexpr size_t WIL_OFF = WIH_OFF + 1024ull * 1024 * 2;

typedef __attribute__((ext_vector_type(8))) short bf16x8;
typedef __attribute__((ext_vector_type(4))) float f32x4;

__device__ __forceinline__ float2 cmul(float2 a, float2 b) {
    return make_float2(a.x * b.x - a.y * b.y, a.x * b.y + a.y * b.x);
}
__device__ __forceinline__ unsigned short f2bf(float f) {
    unsigned u = __float_as_uint(f);
    u += 0x7FFFu + ((u >> 16) & 1u);     // RNE; inputs finite/normal
    return (unsigned short)(u >> 16);
}
__device__ __forceinline__ float bf2f(unsigned short h) {
    return __uint_as_float((unsigned)h << 16);
}

// split fp32 -> bf16 hi + bf16 lo (residual), 4 elems/thread
__global__ __launch_bounds__(256) void split_bf16(const float* __restrict__ src,
                                                  unsigned short* __restrict__ hi,
                                                  unsigned short* __restrict__ lo, int n4) {
    int i = blockIdx.x * 256 + threadIdx.x;
    if (i >= n4) return;
    float4 v = ((const float4*)src)[i];
    unsigned short hx = f2bf(v.x), hy = f2bf(v.y), hz = f2bf(v.z), hw = f2bf(v.w);
    ushort4 h = make_ushort4(hx, hy, hz, hw);
    ushort4 l = make_ushort4(f2bf(v.x - bf2f(hx)), f2bf(v.y - bf2f(hy)),
                             f2bf(v.z - bf2f(hz)), f2bf(v.w - bf2f(hw)));
    ((ushort4*)hi)[i] = h;
    ((ushort4*)lo)[i] = l;
}

// ---------------- radix-16 FFT machinery (N=4096 = 16^3, 3 LDS passes) ----------------
__device__ __forceinline__ int PH(int j) { return j + (j >> 4) + ((j >> 8) << 2); }
__device__ __forceinline__ int DR3(int q) { return ((q & 15) << 8) | (q & 240) | (q >> 8); }

__device__ __forceinline__ void tmul(float2& z, float wx, float wy) {
    z = make_float2(z.x * wx - z.y * wy, z.x * wy + z.y * wx);
}

// In-register 16-point DFT, radix-4 x radix-4. SGN=-1 fwd, +1 inv.
// HZ: inputs r[8..15] structurally zero. OUTPUT PERM: X[u] in slot 4*(u&3)+(u>>2).
template<int SGN, bool HZ>
__device__ __forceinline__ void dft16(float2 r[16]) {
    constexpr float C1 = 0.9238795325112867f;
    constexpr float S1 = 0.3826834323650898f;
    constexpr float R2 = 0.7071067811865476f;
    const float sg = (float)SGN;
#pragma unroll
    for (int t0 = 0; t0 < 4; ++t0) {
        float2 a = r[t0];
        float2 b = r[t0 + 4];
        if (HZ) {
            r[t0]      = make_float2(a.x + b.x, a.y + b.y);
            r[t0 + 8]  = make_float2(a.x - b.x, a.y - b.y);
            r[t0 + 4]  = make_float2(a.x - sg * b.y, a.y + sg * b.x);
            r[t0 + 12] = make_float2(a.x + sg * b.y, a.y - sg * b.x);
        } else {
            float2 c = r[t0 + 8];
            float2 d = r[t0 + 12];
            float2 s0 = make_float2(a.x + c.x, a.y + c.y);
            float2 s1 = make_float2(a.x - c.x, a.y - c.y);
            float2 s2 = make_float2(b.x + d.x, b.y + d.y);
            float2 s3 = make_float2(b.x - d.x, b.y - d.y);
            r[t0]      = make_float2(s0.x + s2.x, s0.y + s2.y);
            r[t0 + 8]  = make_float2(s0.x - s2.x, s0.y - s2.y);
            r[t0 + 4]  = make_float2(s1.x - sg * s3.y, s1.y + sg * s3.x);
            r[t0 + 12] = make_float2(s1.x + sg * s3.y, s1.y - sg * s3.x);
        }
    }
    tmul(r[5],  C1,  sg * S1);
    tmul(r[9],  R2,  sg * R2);
    tmul(r[13], S1,  sg * C1);
    tmul(r[6],  R2,  sg * R2);
    tmul(r[10], 0.f, sg);
    tmul(r[14], -R2, sg * R2);
    tmul(r[7],  S1,  sg * C1);
    tmul(r[11], -R2, sg * R2);
    tmul(r[15], -C1, -sg * S1);
#pragma unroll
    for (int u0 = 0; u0 < 4; ++u0) {
        float2 a = r[4 * u0], b = r[4 * u0 + 1], c = r[4 * u0 + 2], d = r[4 * u0 + 3];
        float2 s0 = make_float2(a.x + c.x, a.y + c.y);
        float2 s1 = make_float2(a.x - c.x, a.y - c.y);
        float2 s2 = make_float2(b.x + d.x, b.y + d.y);
        float2 s3 = make_float2(b.x - d.x, b.y - d.y);
        r[4 * u0]     = make_float2(s0.x + s2.x, s0.y + s2.y);
        r[4 * u0 + 2] = make_float2(s0.x - s2.x, s0.y - s2.y);
        r[4 * u0 + 1] = make_float2(s1.x - sg * s3.y, s1.y + sg * s3.x);
        r[4 * u0 + 3] = make_float2(s1.x + sg * s3.y, s1.y - sg * s3.x);
    }
}

template<int SGN, bool HZ>
__device__ __forceinline__ void fft_pass0(float2* dsh, int tid) {
    float2 r[16];
#pragma unroll
    for (int t = 0; t < (HZ ? 8 : 16); ++t) r[t] = dsh[PH(16 * tid + t)];
    dft16<SGN, HZ>(r);
#pragma unroll
    for (int u = 0; u < 16; ++u) dsh[PH(16 * tid + u)] = r[4 * (u & 3) + (u >> 2)];
}
template<int SGN>
__device__ __forceinline__ void fft_pass1(float2* dsh, int tid) {
    const int j = tid & 15;
    const int base = ((tid >> 4) << 8) + j;
    float2 r[16];
#pragma unroll
    for (int t = 0; t < 16; ++t) r[t] = dsh[PH(base + 16 * t)];
    float sv, cv;
    sincosf((float)SGN * 2.0f * PI_F * (float)j * (1.0f / 256.0f), &sv, &cv);
    float2 w = make_float2(cv, sv), wc = w;
#pragma unroll
    for (int t = 1; t < 16; ++t) { r[t] = cmul(r[t], wc); wc = cmul(wc, w); }
    dft16<SGN, false>(r);
#pragma unroll
    for (int u = 0; u < 16; ++u) dsh[PH(base + 16 * u)] = r[4 * (u & 3) + (u >> 2)];
}
template<int SGN>
__device__ __forceinline__ void fft_pass2(float2* dsh, int tid) {
    float2 r[16];
#pragma unroll
    for (int t = 0; t < 16; ++t) r[t] = dsh[PH(tid + 256 * t)];
    float sv, cv;
    sincosf((float)SGN * 2.0f * PI_F * (float)tid * (1.0f / 4096.0f), &sv, &cv);
    float2 w = make_float2(cv, sv), wc = w;
#pragma unroll
    for (int t = 1; t < 16; ++t) { r[t] = cmul(r[t], wc); wc = cmul(wc, w); }
    dft16<SGN, false>(r);
#pragma unroll
    for (int u = 0; u < 16; ++u) dsh[PH(tid + 256 * u)] = r[4 * (u & 3) + (u >> 2)];
}

__device__ __forceinline__ void fwd_fft_padded(float2* dsh, const float2* row, int tid) {
#pragma unroll
    for (int t = 0; t < 8; ++t) {
        int j = tid + (t << 8);                         // j < 2048; j>>8 == t
        dsh[PH(((j & 15) << 8) | (j & 240) | t)] = row[j];
    }
    __syncthreads();
    fft_pass0<-1, true>(dsh, tid);  __syncthreads();
    fft_pass1<-1>(dsh, tid);        __syncthreads();
    fft_pass2<-1>(dsh, tid);        __syncthreads();
}

// rfft of a length-4096 real row zero-padded to 8192; write UNPACKED half-spectrum as fp16x2.
__global__ __launch_bounds__(TPB, 4) void fft_fwd_h(const float* __restrict__ src,
                                                    __half2* __restrict__ dst) {
    __shared__ float2 dsh[4416];
    const int tid = threadIdx.x;
    const float2* x2 = (const float2*)(src + (size_t)blockIdx.x * 4096);
    fwd_fft_padded(dsh, x2, tid);
    __half2* Xrow = dst + (size_t)blockIdx.x * KSTR;
#pragma unroll
    for (int t = 0; t <= 8; ++t) {
        int k = tid + (t << 8);
        if (k > 2048) break;
        float2 Zk = dsh[PH(k & (NF - 1))];
        float2 Zm = dsh[PH((NF - k) & (NF - 1))];
        float2 Fe = make_float2(0.5f * (Zk.x + Zm.x), 0.5f * (Zk.y - Zm.y));
        float2 Fo = make_float2(0.5f * (Zk.y + Zm.y), -0.5f * (Zk.x - Zm.x));
        float sv, cv;
        sincosf(-PI_F * (float)k * (1.0f / 4096.0f), &sv, &cv);
        Xrow[k] = __floats2half2_rn(Fe.x + cv * Fo.x - sv * Fo.y,
                                    Fe.y + cv * Fo.y + sv * Fo.x);
        if (k < 2048) {
            float2 Fe2 = make_float2(0.5f * (Zm.x + Zk.x), 0.5f * (Zm.y - Zk.y));
            float2 Fo2 = make_float2(0.5f * (Zm.y + Zk.y), -0.5f * (Zm.x - Zk.x));
            Xrow[NF - k] = __floats2half2_rn(Fe2.x + (-cv) * Fo2.x - sv * Fo2.y,
                                             Fe2.y + (-cv) * Fo2.y + sv * Fo2.x);
        }
    }
}

// One block per (d,c) [c = gid&3 so the 4 c-blocks sharing X/xT rows are adjacent]:
// for b=0,1: Y[k] = X[k]*K[k] from fp16 global spectra, packed inverse FFT, + dmat skip, y bf16.
__global__ __launch_bounds__(TPB, 4) void conv_fused(const __half2* __restrict__ Xf,
                                                     const __half2* __restrict__ Kf,
                                                     const float* __restrict__ xT,
                                                     const float* __restrict__ dmat,
                                                     unsigned short* __restrict__ y) {
    __shared__ float2 dsh[4416];
    const int tid = threadIdx.x;
    const int gid = blockIdx.x;
    const int dch = gid >> 2;
    const int c = gid & 3;
    const __half2* Krow = Kf + (size_t)(c * 1024 + dch) * KSTR;
    const float dm = dmat[c * 1024 + dch];
    const float sc = 1.0f / 4096.0f;

#pragma unroll 1
    for (int b = 0; b < 2; ++b) {
        const __half2* Xrow = Xf + (size_t)(b * 1024 + dch) * KSTR;
#pragma unroll 3
        for (int t = 0; t < 9; ++t) {
            int k = tid + (t << 8);
            if (k > 2048) continue;
            float2 Xk = __half22float2(Xrow[k]);
            float2 Kk = __half22float2(Krow[k]);
            float2 Xm = __half22float2(Xrow[NF - k]);
            float2 Km = __half22float2(Krow[NF - k]);
            float2 Yk = cmul(Xk, Kk);
            float2 Ym = cmul(Xm, Km);
            float2 Fe = make_float2(0.5f * (Yk.x + Ym.x), 0.5f * (Yk.y - Ym.y));
            float2 G = make_float2(0.5f * (Yk.x - Ym.x), 0.5f * (Yk.y + Ym.y));
            float sv, cv;
            sincosf(PI_F * (float)k * (1.0f / 4096.0f), &sv, &cv);
            float2 Fo = make_float2(cv * G.x - sv * G.y, cv * G.y + sv * G.x);
            dsh[PH(DR3(k))] = make_float2(Fe.x - Fo.y, Fe.y + Fo.x);
            if (k > 0 && k < 2048) {         // Z[4096-k] = conj(Fe) + i*conj(Fo)
                dsh[PH(DR3(NF - k))] = make_float2(Fe.x + Fo.y, Fo.x - Fe.y);
            }
        }
        __syncthreads();
        fft_pass0<1, false>(dsh, tid); __syncthreads();
        fft_pass1<1>(dsh, tid);        __syncthreads();
        fft_pass2<1>(dsh, tid);        __syncthreads();

        const float2* x2 = (const float2*)(xT + (size_t)(b * 1024 + dch) * 4096);
        unsigned int* yrow =
            (unsigned int*)(y + (size_t)((b * 4 + c) * 1024 + dch) * 4096);
#pragma unroll
        for (int t = 0; t < 8; ++t) {
            int j = tid + (t << 8);
            float2 z = dsh[PH(j)];
            float2 xv = x2[j];
            float r0 = z.x * sc + xv.x * dm;
            float r1 = z.y * sc + xv.y * dm;
            yrow[j] = ((unsigned int)f2bf(r1) << 16) | (unsigned int)f2bf(r0);
        }
        __syncthreads();                     // y written; safe to repack dsh for next b
    }
}

// in-proj via split-bf16 MFMA (pre-split inputs): xT[n][l] = sum_k W[k][n]*u[m][k] + b[n].
__global__ __launch_bounds__(TPB) void gemm_in_mfma(const unsigned short* __restrict__ Uh,
                                                    const unsigned short* __restrict__ Ul,
                                                    const unsigned short* __restrict__ Wh,
                                                    const unsigned short* __restrict__ Wl,
                                                    const float* __restrict__ bias,
                                                    float* __restrict__ xT) {
    __shared__ unsigned short Ah[128][40];   // [n][k]
    __shared__ unsigned short Al[128][40];
    __shared__ unsigned short Bh[128][40];   // [l][k]
    __shared__ unsigned short Bl[128][40];
    const int tid = threadIdx.x;
    const int n0 = blockIdx.x * 128;
    const int mo = blockIdx.y * 128;         // global m = b*4096 + l
    const int b  = mo >> 12;
    const int l0 = mo & 4095;
    const int wave = tid >> 6, lane = tid & 63;
    const int wn = (wave >> 1) * 64;
    const int wl = (wave & 1) * 64;
    const int fr = lane & 15, kg = lane >> 4;

    f32x4 acc[4][4];
#pragma unroll
    for (int i = 0; i < 4; ++i)
#pragma unroll
        for (int j = 0; j < 4; ++j) acc[i][j] = (f32x4){0.f, 0.f, 0.f, 0.f};

    for (int k0 = 0; k0 < 1024; k0 += 32) {
#pragma unroll
        for (int r = 0; r < 2; ++r) {
            int s = tid + (r << 8);          // 0..511
            int n = s & 127, kb = s >> 7;    // kb 0..3
            const unsigned short* wh = Wh + (size_t)(k0 + kb * 8) * 1024 + n0 + n;
            const unsigned short* wll = Wl + (size_t)(k0 + kb * 8) * 1024 + n0 + n;
            bf16x8 h, l;
#pragma unroll
            for (int q = 0; q < 8; ++q) {
                h[q] = (short)wh[(size_t)q * 1024];
                l[q] = (short)wll[(size_t)q * 1024];
            }
            *(bf16x8*)&Ah[n][kb * 8] = h;
            *(bf16x8*)&Al[n][kb * 8] = l;
        }
#pragma unroll
        for (int r = 0; r < 2; ++r) {
            int s = tid + (r << 8);          // 0..511
            int row = s >> 2, kq8 = (s & 3) << 3;
            *(bf16x8*)&Bh[row][kq8] =
                *(const bf16x8*)(Uh + (size_t)(mo + row) * 1024 + k0 + kq8);
            *(bf16x8*)&Bl[row][kq8] =
                *(const bf16x8*)(Ul + (size_t)(mo + row) * 1024 + k0 + kq8);
        }
        __syncthreads();

        bf16x8 ah[4], al[4], bh[4], bl[4];
#pragma unroll
        for (int f = 0; f < 4; ++f) {
            ah[f] = *(const bf16x8*)&Ah[wn + f * 16 + fr][kg * 8];
            al[f] = *(const bf16x8*)&Al[wn + f * 16 + fr][kg * 8];
            bh[f] = *(const bf16x8*)&Bh[wl + f * 16 + fr][kg * 8];
            bl[f] = *(const bf16x8*)&Bl[wl + f * 16 + fr][kg * 8];
        }
#pragma unroll
        for (int i = 0; i < 4; ++i)
#pragma unroll
            for (int j = 0; j < 4; ++j) {
                acc[i][j] = __builtin_amdgcn_mfma_f32_16x16x32_bf16(ah[i], bh[j], acc[i][j], 0, 0, 0);
                acc[i][j] = __builtin_amdgcn_mfma_f32_16x16x32_bf16(ah[i], bl[j], acc[i][j], 0, 0, 0);
                acc[i][j] = __builtin_amdgcn_mfma_f32_16x16x32_bf16(al[i], bh[j], acc[i][j], 0, 0, 0);
            }
        __syncthreads();
    }
#pragma unroll
    for (int i = 0; i < 4; ++i)
#pragma unroll
        for (int j = 0; j < 4; ++j)
#pragma unroll
            for (int rr = 0; rr < 4; ++rr) {
                int ng = n0 + wn + i * 16 + kg * 4 + rr;   // C/D row
                int lg = l0 + wl + j * 16 + fr;            // C/D col
                xT[(size_t)(b * 1024 + ng) * 4096 + lg] = acc[i][j][rr] + bias[ng];
            }
}

// out-proj: out[m][n] = sum_k y[b][k][l]*W[k][n] + bias[n]. A = bf16 y, B = pre-split W hi/lo.
__global__ __launch_bounds__(TPB) void gemm_out_mfma(const unsigned short* __restrict__ Y,
                                                     const unsigned short* __restrict__ Wh,
                                                     const unsigned short* __restrict__ Wl,
                                                     const float* __restrict__ bias,
                                                     float* __restrict__ out) {
    __shared__ unsigned short Ah[128][40];   // [m(l)][k]
    __shared__ unsigned short Bh[128][40];   // [n][k]
    __shared__ unsigned short Bl[128][40];
    const int tid = threadIdx.x;
    const int m0 = blockIdx.x * 128;         // over M = 8192 (b*4096 + l)
    const int n0 = blockIdx.y * 128;
    const int b = m0 >> 12;
    const size_t kbase = (size_t)b * 4096;
    const int wave = tid >> 6, lane = tid & 63;
    const int wm = (wave >> 1) * 64;
    const int wn = (wave & 1) * 64;
    const int fr = lane & 15, kg = lane >> 4;

    f32x4 acc[4][4];
#pragma unroll
    for (int i = 0; i < 4; ++i)
#pragma unroll
        for (int j = 0; j < 4; ++j) acc[i][j] = (f32x4){0.f, 0.f, 0.f, 0.f};

    for (int k0 = 0; k0 < 4096; k0 += 32) {
#pragma unroll
        for (int r = 0; r < 2; ++r) {
            int s = tid + (r << 8);          // 0..511
            int li = s & 127;
            int kb = s >> 7;                 // 0..3 (8 k's each)
            {
                const unsigned short* ap =
                    Y + (kbase + k0 + kb * 8) * 4096 + (m0 & 4095) + li;
                bf16x8 h;
#pragma unroll
                for (int i = 0; i < 8; ++i) h[i] = (short)ap[(size_t)i * 4096];
                *(bf16x8*)&Ah[li][kb * 8] = h;
            }
            {
                const unsigned short* wh = Wh + (size_t)(k0 + kb * 8) * 1024 + n0 + li;
                const unsigned short* wll = Wl + (size_t)(k0 + kb * 8) * 1024 + n0 + li;
                bf16x8 h, l8;
#pragma unroll
                for (int i = 0; i < 8; ++i) {
                    h[i] = (short)wh[(size_t)i * 1024];
                    l8[i] = (short)wll[(size_t)i * 1024];
                }
                *(bf16x8*)&Bh[li][kb * 8] = h;
                *(bf16x8*)&Bl[li][kb * 8] = l8;
            }
        }
        __syncthreads();

        bf16x8 ah[4], bh[4], bl[4];
#pragma unroll
        for (int f = 0; f < 4; ++f) {
            ah[f] = *(const bf16x8*)&Ah[wm + f * 16 + fr][kg * 8];
            bh[f] = *(const bf16x8*)&Bh[wn + f * 16 + fr][kg * 8];
            bl[f] = *(const bf16x8*)&Bl[wn + f * 16 + fr][kg * 8];
        }
#pragma unroll
        for (int i = 0; i < 4; ++i)
#pragma unroll
            for (int j = 0; j < 4; ++j) {
                acc[i][j] = __builtin_amdgcn_mfma_f32_16x16x32_bf16(ah[i], bh[j], acc[i][j], 0, 0, 0);
                acc[i][j] = __builtin_amdgcn_mfma_f32_16x16x32_bf16(ah[i], bl[j], acc[i][j], 0, 0, 0);
            }
        __syncthreads();
    }

    float bj[4];
#pragma unroll
    for (int j = 0; j < 4; ++j) bj[j] = bias[n0 + wn + j * 16 + fr];
#pragma unroll
    for (int i = 0; i < 4; ++i)
#pragma unroll
        for (int j = 0; j < 4; ++j)
#pragma unroll
            for (int r = 0; r < 4; ++r) {
                int m = m0 + wm + i * 16 + kg * 4 + r;
                int n = n0 + wn + j * 16 + fr;
                out[(size_t)m * 1024 + n] = acc[i][j][r] + bj[j];
            }
}

__global__ void ws_fail(float* out, float wssz) {
    out[0] = -12345.0f;
    out[1] = wssz;
}

extern "C" void kernel_launch(void* const* d_in, const int* in_sizes, int n_in,
                              void* d_out, int out_size, void* d_ws, size_t ws_size,
                              hipStream_t stream) {
    (void)in_sizes; (void)n_in; (void)out_size;
    float* out = (float*)d_out;
    if (ws_size < WS_NEED) {                 // sentinel: reports ws_size via validation mismatch
        ws_fail<<<1, 1, 0, stream>>>(out, (float)ws_size);
        return;
    }

    const float* u    = (const float*)d_in[0];
    const float* in_w = (const float*)d_in[1];
    const float* in_b = (const float*)d_in[2];
    const float* kern = (const float*)d_in[3];
    const float* dmat = (const float*)d_in[4];
    const float* outw = (const float*)d_in[5];
    const float* outb = (const float*)d_in[6];

    char* ws = (char*)d_ws;
    float*          xT  = (float*)(ws + XT_OFF);
    __half2*        Xf  = (__half2*)(ws + XF_OFF);
    __half2*        Kf  = (__half2*)(ws + KF_OFF);
    unsigned short* y   = (unsigned short*)(ws + Y_OFF);
    unsigned short* Uh  = (unsigned short*)(ws + UH_OFF);
    unsigned short* Ul  = (unsigned short*)(ws + UL_OFF);
    unsigned short* Wih = (unsigned short*)(ws + WIH_OFF);
    unsigned short* Wil = (unsigned short*)(ws + WIL_OFF);
    unsigned short* Woh = (unsigned short*)(ws + WOH_OFF);
    unsigned short* Wol = (unsigned short*)(ws + WOL_OFF);

    split_bf16<<<dim3(8192), 256, 0, stream>>>(u, Uh, Ul, 8192 * 1024 / 4);
    split_bf16<<<dim3(1024), 256, 0, stream>>>(in_w, Wih, Wil, 1024 * 1024 / 4);
    split_bf16<<<dim3(4096), 256, 0, stream>>>(outw, Woh, Wol, 4096 * 1024 / 4);

    gemm_in_mfma<<<dim3(8, 64), TPB, 0, stream>>>(Uh, Ul, Wih, Wil, in_b, xT);
    fft_fwd_h<<<dim3(2048), TPB, 0, stream>>>(xT, Xf);     // x spectra (overwrites nothing live)
    fft_fwd_h<<<dim3(4096), TPB, 0, stream>>>(kern, Kf);   // kernel spectra (aliases dead Uh..Wil)
    conv_fused<<<dim3(4096), TPB, 0, stream>>>(Xf, Kf, xT, dmat, y);
    gemm_out_mfma<<<dim3(64, 8), TPB, 0, stream>>>(y, Woh, Wol, outb, out);
}

// Round 9
// 627.138 us; speedup vs baseline: 1.3043x; 1.3043x over previous
//
#include <hip/hip_runtime.h>
#include <hip/hip_fp16.h>

#define TPB 256
constexpr float PI_F = 3.14159265358979323846f;

constexpr int NF = 4096;           // complex FFT length (real n = 8192)
constexpr int KSTR = 4104;         // __half2 stride per spectral row (4097 used)

// workspace layout (bytes) — ws_size is 256 MiB; total here ≈ 212.8 MiB
constexpr size_t XT_OFF  = 0;                                     // xT [2][1024][4096] f32 = 32 MiB
constexpr size_t XF_OFF  = 33554432ull;                           // Xf fp16 [2048][KSTR] = 33.6 MiB
constexpr size_t Y_OFF   = XF_OFF + 2048ull * KSTR * 4;           // y bf16 [2][4][1024][4096] = 64 MiB
constexpr size_t KF_OFF  = Y_OFF + 2ull * 4 * 1024 * 4096 * 2;    // Kf fp16 [4096][KSTR] = 67.2 MiB
constexpr size_t WOH_OFF = KF_OFF + 4096ull * KSTR * 4;           // out_w hi/lo (8+8 MiB)
constexpr size_t WOL_OFF = WOH_OFF + 4096ull * 1024 * 2;
constexpr size_t WS_NEED = WOL_OFF + 4096ull * 1024 * 2;
// aliased into KF region (dead after gemm_in): Uh 16M | Ul 16M | Wih 2M | Wil 2M
constexpr size_t UH_OFF  = KF_OFF;
constexpr size_t UL_OFF  = UH_OFF + 8192ull * 1024 * 2;
constexpr size_t WIH_OFF = UL_OFF + 8192ull * 1024 * 2;
constexpr size_t WIL_OFF = WIH_OFF + 1024ull * 1024 * 2;

typedef __attribute__((ext_vector_type(8))) short bf16x8;
typedef __attribute__((ext_vector_type(4))) float f32x4;

__device__ __forceinline__ float2 cmul(float2 a, float2 b) {
    return make_float2(a.x * b.x - a.y * b.y, a.x * b.y + a.y * b.x);
}
__device__ __forceinline__ unsigned short f2bf(float f) {
    unsigned u = __float_as_uint(f);
    u += 0x7FFFu + ((u >> 16) & 1u);     // RNE; inputs finite/normal
    return (unsigned short)(u >> 16);
}
__device__ __forceinline__ float bf2f(unsigned short h) {
    return __uint_as_float((unsigned)h << 16);
}
// native HW trig (v_sin/v_cos): tiny codegen, no libm tables. All call sites
// use |x| <= pi/2 where native accuracy (~2^-21) is far inside the fp16-spectra
// error budget.
__device__ __forceinline__ void fsincos(float x, float* s, float* c) {
    *s = __sinf(x);
    *c = __cosf(x);
}

// split fp32 -> bf16 hi + bf16 lo (residual), 4 elems/thread
__global__ __launch_bounds__(256) void split_bf16(const float* __restrict__ src,
                                                  unsigned short* __restrict__ hi,
                                                  unsigned short* __restrict__ lo, int n4) {
    int i = blockIdx.x * 256 + threadIdx.x;
    if (i >= n4) return;
    float4 v = ((const float4*)src)[i];
    unsigned short hx = f2bf(v.x), hy = f2bf(v.y), hz = f2bf(v.z), hw = f2bf(v.w);
    ushort4 h = make_ushort4(hx, hy, hz, hw);
    ushort4 l = make_ushort4(f2bf(v.x - bf2f(hx)), f2bf(v.y - bf2f(hy)),
                             f2bf(v.z - bf2f(hz)), f2bf(v.w - bf2f(hw)));
    ((ushort4*)hi)[i] = h;
    ((ushort4*)lo)[i] = l;
}

// ---------------- radix-16 FFT machinery (N=4096 = 16^3, 3 LDS passes) ----------------
__device__ __forceinline__ int PH(int j) { return j + (j >> 4) + ((j >> 8) << 2); }
__device__ __forceinline__ int DR3(int q) { return ((q & 15) << 8) | (q & 240) | (q >> 8); }

__device__ __forceinline__ void tmul(float2& z, float wx, float wy) {
    z = make_float2(z.x * wx - z.y * wy, z.x * wy + z.y * wx);
}

// In-register 16-point DFT, radix-4 x radix-4. SGN=-1 fwd, +1 inv.
// HZ: inputs r[8..15] structurally zero. OUTPUT PERM: X[u] in slot 4*(u&3)+(u>>2).
template<int SGN, bool HZ>
__device__ __forceinline__ void dft16(float2 r[16]) {
    constexpr float C1 = 0.9238795325112867f;
    constexpr float S1 = 0.3826834323650898f;
    constexpr float R2 = 0.7071067811865476f;
    const float sg = (float)SGN;
#pragma unroll
    for (int t0 = 0; t0 < 4; ++t0) {
        float2 a = r[t0];
        float2 b = r[t0 + 4];
        if (HZ) {
            r[t0]      = make_float2(a.x + b.x, a.y + b.y);
            r[t0 + 8]  = make_float2(a.x - b.x, a.y - b.y);
            r[t0 + 4]  = make_float2(a.x - sg * b.y, a.y + sg * b.x);
            r[t0 + 12] = make_float2(a.x + sg * b.y, a.y - sg * b.x);
        } else {
            float2 c = r[t0 + 8];
            float2 d = r[t0 + 12];
            float2 s0 = make_float2(a.x + c.x, a.y + c.y);
            float2 s1 = make_float2(a.x - c.x, a.y - c.y);
            float2 s2 = make_float2(b.x + d.x, b.y + d.y);
            float2 s3 = make_float2(b.x - d.x, b.y - d.y);
            r[t0]      = make_float2(s0.x + s2.x, s0.y + s2.y);
            r[t0 + 8]  = make_float2(s0.x - s2.x, s0.y - s2.y);
            r[t0 + 4]  = make_float2(s1.x - sg * s3.y, s1.y + sg * s3.x);
            r[t0 + 12] = make_float2(s1.x + sg * s3.y, s1.y - sg * s3.x);
        }
    }
    tmul(r[5],  C1,  sg * S1);
    tmul(r[9],  R2,  sg * R2);
    tmul(r[13], S1,  sg * C1);
    tmul(r[6],  R2,  sg * R2);
    tmul(r[10], 0.f, sg);
    tmul(r[14], -R2, sg * R2);
    tmul(r[7],  S1,  sg * C1);
    tmul(r[11], -R2, sg * R2);
    tmul(r[15], -C1, -sg * S1);
#pragma unroll
    for (int u0 = 0; u0 < 4; ++u0) {
        float2 a = r[4 * u0], b = r[4 * u0 + 1], c = r[4 * u0 + 2], d = r[4 * u0 + 3];
        float2 s0 = make_float2(a.x + c.x, a.y + c.y);
        float2 s1 = make_float2(a.x - c.x, a.y - c.y);
        float2 s2 = make_float2(b.x + d.x, b.y + d.y);
        float2 s3 = make_float2(b.x - d.x, b.y - d.y);
        r[4 * u0]     = make_float2(s0.x + s2.x, s0.y + s2.y);
        r[4 * u0 + 2] = make_float2(s0.x - s2.x, s0.y - s2.y);
        r[4 * u0 + 1] = make_float2(s1.x - sg * s3.y, s1.y + sg * s3.x);
        r[4 * u0 + 3] = make_float2(s1.x + sg * s3.y, s1.y - sg * s3.x);
    }
}

template<int SGN, bool HZ>
__device__ __forceinline__ void fft_pass0(float2* dsh, int tid) {
    float2 r[16];
#pragma unroll
    for (int t = 0; t < (HZ ? 8 : 16); ++t) r[t] = dsh[PH(16 * tid + t)];
    dft16<SGN, HZ>(r);
#pragma unroll
    for (int u = 0; u < 16; ++u) dsh[PH(16 * tid + u)] = r[4 * (u & 3) + (u >> 2)];
}
template<int SGN>
__device__ __forceinline__ void fft_pass1(float2* dsh, int tid) {
    const int j = tid & 15;
    const int base = ((tid >> 4) << 8) + j;
    float2 r[16];
#pragma unroll
    for (int t = 0; t < 16; ++t) r[t] = dsh[PH(base + 16 * t)];
    float sv, cv;
    fsincos((float)SGN * 2.0f * PI_F * (float)j * (1.0f / 256.0f), &sv, &cv);
    float2 w = make_float2(cv, sv), wc = w;
#pragma unroll
    for (int t = 1; t < 16; ++t) { r[t] = cmul(r[t], wc); wc = cmul(wc, w); }
    dft16<SGN, false>(r);
#pragma unroll
    for (int u = 0; u < 16; ++u) dsh[PH(base + 16 * u)] = r[4 * (u & 3) + (u >> 2)];
}
template<int SGN>
__device__ __forceinline__ void fft_pass2(float2* dsh, int tid) {
    float2 r[16];
#pragma unroll
    for (int t = 0; t < 16; ++t) r[t] = dsh[PH(tid + 256 * t)];
    float sv, cv;
    fsincos((float)SGN * 2.0f * PI_F * (float)tid * (1.0f / 4096.0f), &sv, &cv);
    float2 w = make_float2(cv, sv), wc = w;
#pragma unroll
    for (int t = 1; t < 16; ++t) { r[t] = cmul(r[t], wc); wc = cmul(wc, w); }
    dft16<SGN, false>(r);
#pragma unroll
    for (int u = 0; u < 16; ++u) dsh[PH(tid + 256 * u)] = r[4 * (u & 3) + (u >> 2)];
}

__device__ __forceinline__ void fwd_fft_padded(float2* dsh, const float2* row, int tid) {
#pragma unroll
    for (int t = 0; t < 8; ++t) {
        int j = tid + (t << 8);                         // j < 2048; j>>8 == t
        dsh[PH(((j & 15) << 8) | (j & 240) | t)] = row[j];
    }
    __syncthreads();
    fft_pass0<-1, true>(dsh, tid);  __syncthreads();
    fft_pass1<-1>(dsh, tid);        __syncthreads();
    fft_pass2<-1>(dsh, tid);        __syncthreads();
}

// rfft of a length-4096 real row zero-padded to 8192; write UNPACKED half-spectrum as fp16x2.
__global__ __launch_bounds__(TPB) void fft_fwd_h(const float* __restrict__ src,
                                                 __half2* __restrict__ dst) {
    __shared__ float2 dsh[4416];
    const int tid = threadIdx.x;
    const float2* x2 = (const float2*)(src + (size_t)blockIdx.x * 4096);
    fwd_fft_padded(dsh, x2, tid);
    __half2* Xrow = dst + (size_t)blockIdx.x * KSTR;
#pragma unroll
    for (int t = 0; t <= 8; ++t) {
        int k = tid + (t << 8);
        if (k > 2048) break;
        float2 Zk = dsh[PH(k & (NF - 1))];
        float2 Zm = dsh[PH((NF - k) & (NF - 1))];
        float2 Fe = make_float2(0.5f * (Zk.x + Zm.x), 0.5f * (Zk.y - Zm.y));
        float2 Fo = make_float2(0.5f * (Zk.y + Zm.y), -0.5f * (Zk.x - Zm.x));
        float sv, cv;
        fsincos(-PI_F * (float)k * (1.0f / 4096.0f), &sv, &cv);
        Xrow[k] = __floats2half2_rn(Fe.x + cv * Fo.x - sv * Fo.y,
                                    Fe.y + cv * Fo.y + sv * Fo.x);
        if (k < 2048) {
            float2 Fe2 = make_float2(0.5f * (Zm.x + Zk.x), 0.5f * (Zm.y - Zk.y));
            float2 Fo2 = make_float2(0.5f * (Zm.y + Zk.y), -0.5f * (Zm.x - Zk.x));
            Xrow[NF - k] = __floats2half2_rn(Fe2.x + (-cv) * Fo2.x - sv * Fo2.y,
                                             Fe2.y + (-cv) * Fo2.y + sv * Fo2.x);
        }
    }
}

// One block per (d,c) [c = gid&3 so the 4 c-blocks sharing X/xT rows are adjacent]:
// for b=0,1: Y[k] = X[k]*K[k] from fp16 global spectra, packed inverse FFT, + dmat skip, y bf16.
__global__ __launch_bounds__(TPB) void conv_fused(const __half2* __restrict__ Xf,
                                                  const __half2* __restrict__ Kf,
                                                  const float* __restrict__ xT,
                                                  const float* __restrict__ dmat,
                                                  unsigned short* __restrict__ y) {
    __shared__ float2 dsh[4416];
    const int tid = threadIdx.x;
    const int gid = blockIdx.x;
    const int dch = gid >> 2;
    const int c = gid & 3;
    const __half2* Krow = Kf + (size_t)(c * 1024 + dch) * KSTR;
    const float dm = dmat[c * 1024 + dch];
    const float sc = 1.0f / 4096.0f;

#pragma unroll 1
    for (int b = 0; b < 2; ++b) {
        const __half2* Xrow = Xf + (size_t)(b * 1024 + dch) * KSTR;
#pragma unroll 3
        for (int t = 0; t < 9; ++t) {
            int k = tid + (t << 8);
            if (k > 2048) continue;
            float2 Xk = __half22float2(Xrow[k]);
            float2 Kk = __half22float2(Krow[k]);
            float2 Xm = __half22float2(Xrow[NF - k]);
            float2 Km = __half22float2(Krow[NF - k]);
            float2 Yk = cmul(Xk, Kk);
            float2 Ym = cmul(Xm, Km);
            float2 Fe = make_float2(0.5f * (Yk.x + Ym.x), 0.5f * (Yk.y - Ym.y));
            float2 G = make_float2(0.5f * (Yk.x - Ym.x), 0.5f * (Yk.y + Ym.y));
            float sv, cv;
            fsincos(PI_F * (float)k * (1.0f / 4096.0f), &sv, &cv);
            float2 Fo = make_float2(cv * G.x - sv * G.y, cv * G.y + sv * G.x);
            dsh[PH(DR3(k))] = make_float2(Fe.x - Fo.y, Fe.y + Fo.x);
            if (k > 0 && k < 2048) {         // Z[4096-k] = conj(Fe) + i*conj(Fo)
                dsh[PH(DR3(NF - k))] = make_float2(Fe.x + Fo.y, Fo.x - Fe.y);
            }
        }
        __syncthreads();
        fft_pass0<1, false>(dsh, tid); __syncthreads();
        fft_pass1<1>(dsh, tid);        __syncthreads();
        fft_pass2<1>(dsh, tid);        __syncthreads();

        const float2* x2 = (const float2*)(xT + (size_t)(b * 1024 + dch) * 4096);
        unsigned int* yrow =
            (unsigned int*)(y + (size_t)((b * 4 + c) * 1024 + dch) * 4096);
#pragma unroll
        for (int t = 0; t < 8; ++t) {
            int j = tid + (t << 8);
            float2 z = dsh[PH(j)];
            float2 xv = x2[j];
            float r0 = z.x * sc + xv.x * dm;
            float r1 = z.y * sc + xv.y * dm;
            yrow[j] = ((unsigned int)f2bf(r1) << 16) | (unsigned int)f2bf(r0);
        }
        __syncthreads();                     // y written; safe to repack dsh for next b
    }
}

// in-proj via split-bf16 MFMA (pre-split inputs): xT[n][l] = sum_k W[k][n]*u[m][k] + b[n].
__global__ __launch_bounds__(TPB) void gemm_in_mfma(const unsigned short* __restrict__ Uh,
                                                    const unsigned short* __restrict__ Ul,
                                                    const unsigned short* __restrict__ Wh,
                                                    const unsigned short* __restrict__ Wl,
                                                    const float* __restrict__ bias,
                                                    float* __restrict__ xT) {
    __shared__ unsigned short Ah[128][40];   // [n][k]
    __shared__ unsigned short Al[128][40];
    __shared__ unsigned short Bh[128][40];   // [l][k]
    __shared__ unsigned short Bl[128][40];
    const int tid = threadIdx.x;
    const int n0 = blockIdx.x * 128;
    const int mo = blockIdx.y * 128;         // global m = b*4096 + l
    const int b  = mo >> 12;
    const int l0 = mo & 4095;
    const int wave = tid >> 6, lane = tid & 63;
    const int wn = (wave >> 1) * 64;
    const int wl = (wave & 1) * 64;
    const int fr = lane & 15, kg = lane >> 4;

    f32x4 acc[4][4];
#pragma unroll
    for (int i = 0; i < 4; ++i)
#pragma unroll
        for (int j = 0; j < 4; ++j) acc[i][j] = (f32x4){0.f, 0.f, 0.f, 0.f};

    for (int k0 = 0; k0 < 1024; k0 += 32) {
#pragma unroll
        for (int r = 0; r < 2; ++r) {
            int s = tid + (r << 8);          // 0..511
            int n = s & 127, kb = s >> 7;    // kb 0..3
            const unsigned short* wh = Wh + (size_t)(k0 + kb * 8) * 1024 + n0 + n;
            const unsigned short* wll = Wl + (size_t)(k0 + kb * 8) * 1024 + n0 + n;
            bf16x8 h, l;
#pragma unroll
            for (int q = 0; q < 8; ++q) {
                h[q] = (short)wh[(size_t)q * 1024];
                l[q] = (short)wll[(size_t)q * 1024];
            }
            *(bf16x8*)&Ah[n][kb * 8] = h;
            *(bf16x8*)&Al[n][kb * 8] = l;
        }
#pragma unroll
        for (int r = 0; r < 2; ++r) {
            int s = tid + (r << 8);          // 0..511
            int row = s >> 2, kq8 = (s & 3) << 3;
            *(bf16x8*)&Bh[row][kq8] =
                *(const bf16x8*)(Uh + (size_t)(mo + row) * 1024 + k0 + kq8);
            *(bf16x8*)&Bl[row][kq8] =
                *(const bf16x8*)(Ul + (size_t)(mo + row) * 1024 + k0 + kq8);
        }
        __syncthreads();

        bf16x8 ah[4], al[4], bh[4], bl[4];
#pragma unroll
        for (int f = 0; f < 4; ++f) {
            ah[f] = *(const bf16x8*)&Ah[wn + f * 16 + fr][kg * 8];
            al[f] = *(const bf16x8*)&Al[wn + f * 16 + fr][kg * 8];
            bh[f] = *(const bf16x8*)&Bh[wl + f * 16 + fr][kg * 8];
            bl[f] = *(const bf16x8*)&Bl[wl + f * 16 + fr][kg * 8];
        }
#pragma unroll
        for (int i = 0; i < 4; ++i)
#pragma unroll
            for (int j = 0; j < 4; ++j) {
                acc[i][j] = __builtin_amdgcn_mfma_f32_16x16x32_bf16(ah[i], bh[j], acc[i][j], 0, 0, 0);
                acc[i][j] = __builtin_amdgcn_mfma_f32_16x16x32_bf16(ah[i], bl[j], acc[i][j], 0, 0, 0);
                acc[i][j] = __builtin_amdgcn_mfma_f32_16x16x32_bf16(al[i], bh[j], acc[i][j], 0, 0, 0);
            }
        __syncthreads();
    }
#pragma unroll
    for (int i = 0; i < 4; ++i)
#pragma unroll
        for (int j = 0; j < 4; ++j)
#pragma unroll
            for (int rr = 0; rr < 4; ++rr) {
                int ng = n0 + wn + i * 16 + kg * 4 + rr;   // C/D row
                int lg = l0 + wl + j * 16 + fr;            // C/D col
                xT[(size_t)(b * 1024 + ng) * 4096 + lg] = acc[i][j][rr] + bias[ng];
            }
}

// out-proj: out[m][n] = sum_k y[b][k][l]*W[k][n] + bias[n]. A = bf16 y, B = pre-split W hi/lo.
__global__ __launch_bounds__(TPB) void gemm_out_mfma(const unsigned short* __restrict__ Y,
                                                     const unsigned short* __restrict__ Wh,
                                                     const unsigned short* __restrict__ Wl,
                                                     const float* __restrict__ bias,
                                                     float* __restrict__ out) {
    __shared__ unsigned short Ah[128][40];   // [m(l)][k]
    __shared__ unsigned short Bh[128][40];   // [n][k]
    __shared__ unsigned short Bl[128][40];
    const int tid = threadIdx.x;
    const int m0 = blockIdx.x * 128;         // over M = 8192 (b*4096 + l)
    const int n0 = blockIdx.y * 128;
    const int b = m0 >> 12;
    const size_t kbase = (size_t)b * 4096;
    const int wave = tid >> 6, lane = tid & 63;
    const int wm = (wave >> 1) * 64;
    const int wn = (wave & 1) * 64;
    const int fr = lane & 15, kg = lane >> 4;

    f32x4 acc[4][4];
#pragma unroll
    for (int i = 0; i < 4; ++i)
#pragma unroll
        for (int j = 0; j < 4; ++j) acc[i][j] = (f32x4){0.f, 0.f, 0.f, 0.f};

    for (int k0 = 0; k0 < 4096; k0 += 32) {
#pragma unroll
        for (int r = 0; r < 2; ++r) {
            int s = tid + (r << 8);          // 0..511
            int li = s & 127;
            int kb = s >> 7;                 // 0..3 (8 k's each)
            {
                const unsigned short* ap =
                    Y + (kbase + k0 + kb * 8) * 4096 + (m0 & 4095) + li;
                bf16x8 h;
#pragma unroll
                for (int i = 0; i < 8; ++i) h[i] = (short)ap[(size_t)i * 4096];
                *(bf16x8*)&Ah[li][kb * 8] = h;
            }
            {
                const unsigned short* wh = Wh + (size_t)(k0 + kb * 8) * 1024 + n0 + li;
                const unsigned short* wll = Wl + (size_t)(k0 + kb * 8) * 1024 + n0 + li;
                bf16x8 h, l8;
#pragma unroll
                for (int i = 0; i < 8; ++i) {
                    h[i] = (short)wh[(size_t)i * 1024];
                    l8[i] = (short)wll[(size_t)i * 1024];
                }
                *(bf16x8*)&Bh[li][kb * 8] = h;
                *(bf16x8*)&Bl[li][kb * 8] = l8;
            }
        }
        __syncthreads();

        bf16x8 ah[4], bh[4], bl[4];
#pragma unroll
        for (int f = 0; f < 4; ++f) {
            ah[f] = *(const bf16x8*)&Ah[wm + f * 16 + fr][kg * 8];
            bh[f] = *(const bf16x8*)&Bh[wn + f * 16 + fr][kg * 8];
            bl[f] = *(const bf16x8*)&Bl[wn + f * 16 + fr][kg * 8];
        }
#pragma unroll
        for (int i = 0; i < 4; ++i)
#pragma unroll
            for (int j = 0; j < 4; ++j) {
                acc[i][j] = __builtin_amdgcn_mfma_f32_16x16x32_bf16(ah[i], bh[j], acc[i][j], 0, 0, 0);
                acc[i][j] = __builtin_amdgcn_mfma_f32_16x16x32_bf16(ah[i], bl[j], acc[i][j], 0, 0, 0);
            }
        __syncthreads();
    }

    float bj[4];
#pragma unroll
    for (int j = 0; j < 4; ++j) bj[j] = bias[n0 + wn + j * 16 + fr];
#pragma unroll
    for (int i = 0; i < 4; ++i)
#pragma unroll
        for (int j = 0; j < 4; ++j)
#pragma unroll
            for (int r = 0; r < 4; ++r) {
                int m = m0 + wm + i * 16 + kg * 4 + r;
                int n = n0 + wn + j * 16 + fr;
                out[(size_t)m * 1024 + n] = acc[i][j][r] + bj[j];
            }
}

__global__ void ws_fail(float* out, float wssz) {
    out[0] = -12345.0f;
    out[1] = wssz;
}

extern "C" void kernel_launch(void* const* d_in, const int* in_sizes, int n_in,
                              void* d_out, int out_size, void* d_ws, size_t ws_size,
                              hipStream_t stream) {
    (void)in_sizes; (void)n_in; (void)out_size;
    float* out = (float*)d_out;
    if (ws_size < WS_NEED) {                 // sentinel: reports ws_size via validation mismatch
        ws_fail<<<1, 1, 0, stream>>>(out, (float)ws_size);
        return;
    }

    const float* u    = (const float*)d_in[0];
    const float* in_w = (const float*)d_in[1];
    const float* in_b = (const float*)d_in[2];
    const float* kern = (const float*)d_in[3];
    const float* dmat = (const float*)d_in[4];
    const float* outw = (const float*)d_in[5];
    const float* outb = (const float*)d_in[6];

    char* ws = (char*)d_ws;
    float*          xT  = (float*)(ws + XT_OFF);
    __half2*        Xf  = (__half2*)(ws + XF_OFF);
    __half2*        Kf  = (__half2*)(ws + KF_OFF);
    unsigned short* y   = (unsigned short*)(ws + Y_OFF);
    unsigned short* Uh  = (unsigned short*)(ws + UH_OFF);
    unsigned short* Ul  = (unsigned short*)(ws + UL_OFF);
    unsigned short* Wih = (unsigned short*)(ws + WIH_OFF);
    unsigned short* Wil = (unsigned short*)(ws + WIL_OFF);
    unsigned short* Woh = (unsigned short*)(ws + WOH_OFF);
    unsigned short* Wol = (unsigned short*)(ws + WOL_OFF);

    split_bf16<<<dim3(8192), 256, 0, stream>>>(u, Uh, Ul, 8192 * 1024 / 4);
    split_bf16<<<dim3(1024), 256, 0, stream>>>(in_w, Wih, Wil, 1024 * 1024 / 4);
    split_bf16<<<dim3(4096), 256, 0, stream>>>(outw, Woh, Wol, 4096 * 1024 / 4);

    gemm_in_mfma<<<dim3(8, 64), TPB, 0, stream>>>(Uh, Ul, Wih, Wil, in_b, xT);
    fft_fwd_h<<<dim3(2048), TPB, 0, stream>>>(xT, Xf);     // x spectra
    fft_fwd_h<<<dim3(4096), TPB, 0, stream>>>(kern, Kf);   // kernel spectra (aliases dead Uh..Wil)
    conv_fused<<<dim3(4096), TPB, 0, stream>>>(Xf, Kf, xT, dmat, y);
    gemm_out_mfma<<<dim3(64, 8), TPB, 0, stream>>>(y, Woh, Wol, outb, out);
}